// Round 2
// baseline (3724.222 us; speedup 1.0000x reference)
//
#include <hip/hip_runtime.h>
#include <math.h>

// Problem constants
#define B_   256
#define T_   100
#define IN_  132
#define OUT_ 132
#define H_   1024
#define BH   ((size_t)B_ * H_)
#define WSZ  ((size_t)4096 * H_)

typedef _Float16 f16;
typedef _Float16 f16x8 __attribute__((ext_vector_type(8)));
typedef float    f32x4 __attribute__((ext_vector_type(4)));

#define MFMA16(a, b, c) __builtin_amdgcn_mfma_f32_16x16x32_f16((a), (b), (c), 0, 0, 0)

#define AS1 __attribute__((address_space(1)))
#define AS3 __attribute__((address_space(3)))

__device__ __forceinline__ void gl_lds16(const void* g, void* l) {
    __builtin_amdgcn_global_load_lds((AS1 void*)g, (AS3 void*)l, 16, 0, 0);
}

__device__ __forceinline__ float sigmoidf_(float x) {
    return 1.0f / (1.0f + __expf(-x));
}
__device__ __forceinline__ float tanhf_(float x) {
    float e = __expf(2.0f * x);
    return 1.0f - 2.0f / (e + 1.0f);
}

// ---------------- prep kernels ----------------

__global__ void conv_pad(const float* __restrict__ src, f16* __restrict__ dst,
                         int src_rows, int src_k, int dst_k) {
    int k = blockIdx.x * 256 + threadIdx.x;
    int r = blockIdx.y;
    if (k >= dst_k) return;
    float v = (r < src_rows && k < src_k) ? src[(size_t)r * src_k + k] : 0.0f;
    dst[(size_t)r * dst_k + k] = (f16)v;
}

// seq fp32 [B][T][IN] -> fp16 padded [B][T][160]
__global__ void seq_pad(const float* __restrict__ src, f16* __restrict__ dst) {
    int k  = threadIdx.x;
    int bt = blockIdx.y;
    if (k >= 160) return;
    float v = (k < IN_) ? src[(size_t)bt * IN_ + k] : 0.0f;
    dst[(size_t)bt * 160 + k] = (f16)v;
}

// WdT[m][k] = Wd[k][m], padded to k<160. grid (1, 1024), block 256
__global__ void convT_kernel(const float* __restrict__ Wd, f16* __restrict__ WdT) {
    int k = blockIdx.x * 256 + threadIdx.x;
    int m = blockIdx.y;
    if (k >= 160) return;
    float v = (k < IN_) ? Wd[(size_t)k * H_ + m] : 0.0f;
    WdT[(size_t)m * 160 + k] = (f16)v;
}

__global__ void bias_add_kernel(const float* __restrict__ a, const float* __restrict__ b,
                                float* __restrict__ dst, int n) {
    int i = blockIdx.x * 256 + threadIdx.x;
    if (i < n) dst[i] = a[i] + b[i];
}

// bfb[j] = sum_k Wih1[j][k] * bd[k]
__global__ void bfb_kernel(const float* __restrict__ Wih1, const float* __restrict__ bd,
                           float* __restrict__ bfb) {
    int j = blockIdx.x * 256 + threadIdx.x;
    if (j >= 4096) return;
    float s = 0.0f;
    for (int k = 0; k < IN_; ++k) s += Wih1[(size_t)j * IN_ + k] * bd[k];
    bfb[j] = s;
}

__global__ void zero_kernel(float* __restrict__ p, int n) {
    int i = blockIdx.x * blockDim.x + threadIdx.x;
    int st = gridDim.x * blockDim.x;
    for (; i < n; i += st) p[i] = 0.0f;
}

// Wfb = W0(fp16,[4096][160]) @ WdT(fp16,[1024][160])^T -> [4096][1024] fp16
// grid (32 m-tiles, 8 n-tiles), block 256 (4 waves 2x2 of 64x64)
__global__ __launch_bounds__(256) void wfb_mfma(
    const f16* __restrict__ W0, const f16* __restrict__ WdT, f16* __restrict__ Wfb)
{
    const int m0 = blockIdx.x * 128;
    const int n0 = blockIdx.y * 128;
    const int tid  = threadIdx.x;
    const int lane = tid & 63;
    const int w    = tid >> 6;
    const int lx   = lane & 15;
    const int quad = lane >> 4;
    const int wrow = w >> 1, wcol = w & 1;

    __shared__ __align__(16) char lds[32768];   // 2 x (A 8KB + B 8KB)

    auto stA = [&](int kt, int buf) {
        char* base = lds + buf * 16384;
#pragma unroll
        for (int i = 0; i < 2; ++i) {
            int r  = w * 32 + i * 16 + (lane >> 2);
            int sg = (lane & 3) ^ (r & 3);
            const f16* g = W0 + (size_t)(m0 + r) * 160 + kt * 32 + sg * 8;
            gl_lds16(g, base + (size_t)(w * 32 + i * 16) * 64);
        }
    };
    auto stB = [&](int kt, int buf) {
        char* base = lds + 8192 + buf * 16384;
#pragma unroll
        for (int i = 0; i < 2; ++i) {
            int r  = w * 32 + i * 16 + (lane >> 2);
            int sg = (lane & 3) ^ (r & 3);
            const f16* g = WdT + (size_t)(n0 + r) * 160 + kt * 32 + sg * 8;
            gl_lds16(g, base + (size_t)(w * 32 + i * 16) * 64);
        }
    };

    f32x4 acc[4][4];
#pragma unroll
    for (int m = 0; m < 4; ++m)
#pragma unroll
        for (int n = 0; n < 4; ++n) acc[m][n] = (f32x4){0.f, 0.f, 0.f, 0.f};

    stA(0, 0); stB(0, 0);
    for (int kt = 0; kt < 5; ++kt) {
        __syncthreads();
        if (kt + 1 < 5) { stA(kt + 1, (kt + 1) & 1); stB(kt + 1, (kt + 1) & 1); }
        const char* bA = lds + (kt & 1) * 16384;
        const char* bB = lds + 8192 + (kt & 1) * 16384;
        f16x8 af[4], bf[4];
#pragma unroll
        for (int m = 0; m < 4; ++m) {
            int R = wrow * 64 + m * 16 + lx;
            af[m] = *(const f16x8*)(bA + R * 64 + ((quad ^ (R & 3)) * 16));
        }
#pragma unroll
        for (int n = 0; n < 4; ++n) {
            int R = wcol * 64 + n * 16 + lx;
            bf[n] = *(const f16x8*)(bB + R * 64 + ((quad ^ (R & 3)) * 16));
        }
#pragma unroll
        for (int m = 0; m < 4; ++m)
#pragma unroll
            for (int n = 0; n < 4; ++n)
                acc[m][n] = MFMA16(af[m], bf[n], acc[m][n]);
    }

#pragma unroll
    for (int m = 0; m < 4; ++m)
#pragma unroll
        for (int n = 0; n < 4; ++n)
#pragma unroll
            for (int r = 0; r < 4; ++r) {
                int row = m0 + wrow * 64 + m * 16 + quad * 4 + r;
                int col = n0 + wcol * 64 + n * 16 + lx;
                Wfb[(size_t)row * H_ + col] = (f16)acc[m][n][r];
            }
}

// ---------------- fused per-step kernel ----------------
// grid (64 j-tiles, 3 cells), block 512 = 8 waves = 2 teams x 4 waves.
// Block tile: FULL batch 256 x 64 cols (16 j x 4 gates; col c: gate=c>>4, jj=c&15).
// Team 0: input matmul (x@W0 | h2fb@Wfb | h_{l-1}@Wih), team 1: recurrent (h_l@Whh).
// Each team: private 4-buffer pipeline (20KB/buf), 3-deep counted vmcnt, shared
// block barriers (both teams run exactly 32 iterations). Weights read ONCE per step.
// Teams combine via padded LDS f32 exchange; team0 does lane-local LSTM epilogue.
__global__ __launch_bounds__(512) void step_mfma(
    const f16* __restrict__ seq16,    // [B][T][160] fp16 padded
    const f16* __restrict__ hfb,      // h2(t-1) for feedback (valid t>0)
    const f16* __restrict__ h2old,    // h2(t-1) for cell2 recurrent (zeros at t=0)
    const f16* __restrict__ h01c,     // [2][BH] old h0,h1
    f16* __restrict__ h01n,           // [2][BH] new h0,h1
    f16* __restrict__ h2out,          // hist + t*BH
    float* __restrict__ c_st,         // [3][B][H]
    const f16* __restrict__ W0,       // [4096][160]  (Wih1 padded)
    const f16* __restrict__ Wb,       // [5][4096][1024] {Whh1,Wih2,Whh2,Wih3,Whh3}
    const f16* __restrict__ Wfb,      // [4096][1024]  (Wih1 @ Wd)
    const float* __restrict__ bias_comb,  // [3][4096]
    const float* __restrict__ bfb,        // [4096]
    const int* __restrict__ cnum, const int* __restrict__ gnum,
    int t)
{
    extern __shared__ __align__(16) char lds[];   // 163840 B: 2 teams x 4 x 20KB

    const int j0   = blockIdx.x * 16;
    const int l    = blockIdx.y;
    const int tid  = threadIdx.x;
    const int lane = tid & 63;
    const int w    = tid >> 6;
    const int team = w >> 2;
    const int w4   = w & 3;
    const int lx   = lane & 15;
    const int quad = lane >> 4;

    // ---- per-team operand decode
    bool use_gt = false;
    int nt = 32;
    size_t ldA = H_, ldk = H_;
    const f16 *Ap = h01c, *Wp = Wb;
    if (team == 0) {
        if (l == 0) {
            int cn = cnum[0], gn = gnum[0];
            use_gt = (t % (cn + gn)) < gn;
            if (use_gt)      { Ap = seq16 + (size_t)t * 160; ldA = (size_t)T_ * 160;
                               Wp = W0; ldk = 160; nt = 5; }
            else if (t == 0) { nt = 0; }
            else             { Ap = hfb; Wp = Wfb; }
        } else if (l == 1) { Ap = h01c;      Wp = Wb + 1 * WSZ; }
        else               { Ap = h01c + BH; Wp = Wb + 3 * WSZ; }
    } else {
        Ap = (l == 0) ? h01c : (l == 1) ? (h01c + BH) : h2old;
        Wp = Wb + (size_t)((l == 0) ? 0 : (l == 1) ? 2 : 4) * WSZ;
    }

    // ---- staging: per team-wave, 5 x gl_lds16 per stage (A: 4, B: 1)
    char* tb = lds + team * 81920;
    auto stage = [&](int kt, int buf) {
        char* base = tb + buf * 20480;
#pragma unroll
        for (int i = 0; i < 4; ++i) {
            int row = w4 * 64 + i * 16 + (lane >> 2);
            int sg  = (lane & 3) ^ (row & 3);
            gl_lds16(Ap + (size_t)row * ldA + kt * 32 + sg * 8,
                     base + (size_t)(w4 * 64 + i * 16) * 64);
        }
        {
            int c  = w4 * 16 + (lane >> 2);        // gate = c>>4 == w4
            int sg = (lane & 3) ^ (c & 3);
            gl_lds16(Wp + (size_t)(w4 * H_ + j0 + (c & 15)) * ldk + kt * 32 + sg * 8,
                     base + 16384 + (size_t)w4 * 1024);
        }
    };

    f32x4 acc[4][4];
#pragma unroll
    for (int m = 0; m < 4; ++m)
#pragma unroll
        for (int n = 0; n < 4; ++n) acc[m][n] = (f32x4){0.f, 0.f, 0.f, 0.f};

    // ---- 3-deep prologue
    if (0 < nt) stage(0, 0);
    if (1 < nt) stage(1, 1);
    if (2 < nt) stage(2, 2);

    for (int kt = 0; kt < 32; ++kt) {
        const bool act = kt < nt;
        if (act) {
            if (kt < nt - 2)       asm volatile("s_waitcnt vmcnt(10)" ::: "memory");
            else if (kt == nt - 2) asm volatile("s_waitcnt vmcnt(5)" ::: "memory");
            else                   asm volatile("s_waitcnt vmcnt(0)" ::: "memory");
        }
        __builtin_amdgcn_s_barrier();              // stage kt visible to team

        f16x8 af[4], bf[4];
        if (act) {
            const char* bA = tb + (kt & 3) * 20480;
            const char* bB = bA + 16384;
#pragma unroll
            for (int m = 0; m < 4; ++m) {
                int R = w4 * 64 + m * 16 + lx;
                af[m] = *(const f16x8*)(bA + R * 64 + ((quad ^ (R & 3)) * 16));
            }
#pragma unroll
            for (int n = 0; n < 4; ++n) {
                int R = n * 16 + lx;
                bf[n] = *(const f16x8*)(bB + R * 64 + ((quad ^ (R & 3)) * 16));
            }
        }
        asm volatile("s_waitcnt lgkmcnt(0)" ::: "memory");
        __builtin_amdgcn_sched_barrier(0);
        __builtin_amdgcn_s_barrier();              // reads done -> safe to overwrite

        if (kt + 3 < nt) stage(kt + 3, (kt + 3) & 3);

        if (act) {
            __builtin_amdgcn_s_setprio(1);
#pragma unroll
            for (int m = 0; m < 4; ++m)
#pragma unroll
                for (int n = 0; n < 4; ++n)
                    acc[m][n] = MFMA16(af[m], bf[n], acc[m][n]);
            __builtin_amdgcn_s_setprio(0);
        }
    }

    // ---- team combine via padded LDS exchange (stride 68 words: 2-way conflicts only)
    __syncthreads();
    float* exch = (float*)(lds + 81920);
    if (team == 1) {
#pragma unroll
        for (int m = 0; m < 4; ++m)
#pragma unroll
            for (int n = 0; n < 4; ++n)
#pragma unroll
                for (int r = 0; r < 4; ++r) {
                    int row = w4 * 64 + m * 16 + quad * 4 + r;
                    exch[row * 68 + n * 16 + lx] = acc[m][n][r];
                }
    }
    __syncthreads();

    // ---- lane-local LSTM epilogue (team 0 only; j = j0+lx, gates = n)
    if (team == 0) {
        const int j = j0 + lx;
        const float* bc = bias_comb + l * 4096;
        const bool addfb = (l == 0 && !use_gt && t > 0);
        float bi  = bc[j]        + (addfb ? bfb[j]        : 0.f);
        float bff = bc[1024 + j] + (addfb ? bfb[1024 + j] : 0.f);
        float bg  = bc[2048 + j] + (addfb ? bfb[2048 + j] : 0.f);
        float bo  = bc[3072 + j] + (addfb ? bfb[3072 + j] : 0.f);
#pragma unroll
        for (int m = 0; m < 4; ++m) {
#pragma unroll
            for (int r = 0; r < 4; ++r) {
                int b = w4 * 64 + m * 16 + quad * 4 + r;
                float gi = acc[m][0][r] + exch[b * 68 + lx]      + bi;
                float gf = acc[m][1][r] + exch[b * 68 + 16 + lx] + bff;
                float gg = acc[m][2][r] + exch[b * 68 + 32 + lx] + bg;
                float go = acc[m][3][r] + exch[b * 68 + 48 + lx] + bo;
                size_t ix = ((size_t)l * B_ + b) * H_ + j;
                float cn2 = sigmoidf_(gf) * c_st[ix] + sigmoidf_(gi) * tanhf_(gg);
                c_st[ix] = cn2;
                float hv = sigmoidf_(go) * tanhf_(cn2);
                if (l == 2) h2out[(size_t)b * H_ + j] = (f16)hv;
                else        h01n[(size_t)l * BH + (size_t)b * H_ + j] = (f16)hv;
            }
        }
    }
}

// ---------------- final batched decoder ----------------
// out[b][t][n] = hist[t][b][:] @ Wd^T + bd. M=25600 rows (t*256+b), N=160(132), K=1024.
// grid (200, 5), block 256 (4 waves stacked on M; tile 128x32).
__global__ __launch_bounds__(256) void decode_mfma(
    const f16* __restrict__ hist,   // [100][256][1024]
    const f16* __restrict__ Wd16,   // [160][1024]
    const float* __restrict__ bd,   // [132]
    float* __restrict__ dout)       // [256][T*132]
{
    const int r0  = blockIdx.x * 128;
    const int nb0 = blockIdx.y * 32;
    const int tid  = threadIdx.x;
    const int lane = tid & 63;
    const int w    = tid >> 6;
    const int lx   = lane & 15;
    const int quad = lane >> 4;

    __shared__ __align__(16) char lds[20480];   // 2 x (A 8KB + B 2KB)

    auto stA = [&](int kt, int buf) {
        char* base = lds + buf * 10240;
#pragma unroll
        for (int i = 0; i < 2; ++i) {
            int r  = w * 32 + i * 16 + (lane >> 2);
            int sg = (lane & 3) ^ (r & 3);
            const f16* g = hist + (size_t)(r0 + r) * H_ + kt * 32 + sg * 8;
            gl_lds16(g, base + (size_t)(w * 32 + i * 16) * 64);
        }
    };
    auto stB = [&](int kt, int buf) {
        char* base = lds + 8192 + buf * 10240;
        if (w < 2) {
            int r  = w * 16 + (lane >> 2);
            int sg = (lane & 3) ^ (r & 3);
            const f16* g = Wd16 + (size_t)(nb0 + r) * H_ + kt * 32 + sg * 8;
            gl_lds16(g, base + (size_t)(w * 16) * 64);
        }
    };

    f32x4 acc[2][2];
#pragma unroll
    for (int m = 0; m < 2; ++m)
#pragma unroll
        for (int n = 0; n < 2; ++n) acc[m][n] = (f32x4){0.f, 0.f, 0.f, 0.f};

    stA(0, 0); stB(0, 0);
    for (int kt = 0; kt < 32; ++kt) {
        __syncthreads();
        if (kt + 1 < 32) { stA(kt + 1, (kt + 1) & 1); stB(kt + 1, (kt + 1) & 1); }
        const char* bA = lds + (kt & 1) * 10240;
        const char* bB = lds + 8192 + (kt & 1) * 10240;
        f16x8 af[2], bf[2];
#pragma unroll
        for (int m = 0; m < 2; ++m) {
            int R = w * 32 + m * 16 + lx;
            af[m] = *(const f16x8*)(bA + R * 64 + ((quad ^ (R & 3)) * 16));
        }
#pragma unroll
        for (int n = 0; n < 2; ++n) {
            int R = n * 16 + lx;
            bf[n] = *(const f16x8*)(bB + R * 64 + ((quad ^ (R & 3)) * 16));
        }
#pragma unroll
        for (int m = 0; m < 2; ++m)
#pragma unroll
            for (int n = 0; n < 2; ++n)
                acc[m][n] = MFMA16(af[m], bf[n], acc[m][n]);
    }

#pragma unroll
    for (int n = 0; n < 2; ++n) {
        int nn = nb0 + n * 16 + lx;
        if (nn < OUT_) {
            float bv = bd[nn];
#pragma unroll
            for (int m = 0; m < 2; ++m)
#pragma unroll
                for (int r = 0; r < 4; ++r) {
                    int row = r0 + w * 32 + m * 16 + quad * 4 + r;
                    int tt = row >> 8, b = row & 255;
                    dout[(size_t)b * (T_ * OUT_) + (size_t)tt * OUT_ + nn] = acc[m][n][r] + bv;
                }
        }
    }
}

// ---------------- host launch ----------------

extern "C" void kernel_launch(void* const* d_in, const int* in_sizes, int n_in,
                              void* d_out, int out_size, void* d_ws, size_t ws_size,
                              hipStream_t stream) {
    const float* seq  = (const float*)d_in[0];
    const float* Wih1 = (const float*)d_in[1];
    const float* Whh1 = (const float*)d_in[2];
    const float* bih1 = (const float*)d_in[3];
    const float* bhh1 = (const float*)d_in[4];
    const float* Wih2 = (const float*)d_in[5];
    const float* Whh2 = (const float*)d_in[6];
    const float* bih2 = (const float*)d_in[7];
    const float* bhh2 = (const float*)d_in[8];
    const float* Wih3 = (const float*)d_in[9];
    const float* Whh3 = (const float*)d_in[10];
    const float* bih3 = (const float*)d_in[11];
    const float* bhh3 = (const float*)d_in[12];
    const float* Wd   = (const float*)d_in[13];
    const float* bd   = (const float*)d_in[14];
    const int*   cnum = (const int*)d_in[15];
    const int*   gnum = (const int*)d_in[16];

    // ---- workspace layout
    char* p = (char*)d_ws;
    f16*  W0   = (f16*)p;  p += (size_t)4096 * 160 * 2;          // 1.31 MB
    f16*  Wb   = (f16*)p;  p += (size_t)5 * 4096 * 1024 * 2;     // 41.9 MB
    f16*  Wd16 = (f16*)p;  p += (size_t)160 * 1024 * 2;          // 0.33 MB
    f16*  WdT  = (f16*)p;  p += (size_t)1024 * 160 * 2;          // 0.33 MB
    f16*  Wfb  = (f16*)p;  p += (size_t)4096 * 1024 * 2;         // 8.39 MB
    float* bias_comb = (float*)p; p += (size_t)3 * 4096 * 4;     // 48 KB
    float* bfb = (float*)p; p += (size_t)4096 * 4;               // 16 KB
    f16*  hist = (f16*)p;  p += (size_t)100 * BH * 2;            // 52.4 MB
    f16*  h01a = (f16*)p;  p += (size_t)2 * BH * 2;              // 1.05 MB (zeroed)
    f16*  h01b = (f16*)p;  p += (size_t)2 * BH * 2;              // 1.05 MB
    float* c_st = (float*)p; p += (size_t)3 * BH * 4;            // 3.15 MB
    f16*  seq16 = (f16*)p; p += (size_t)B_ * T_ * 160 * 2;       // 8.19 MB
    // zero region: h01a + h01b + c (contiguous)
    const int zero_floats = (int)(((size_t)4 * BH * 2 + (size_t)3 * BH * 4) / 4);

    // allow 160KB dynamic LDS for the step kernel (full CU pool, 1 block/CU)
    hipFuncSetAttribute((const void*)step_mfma,
                        hipFuncAttributeMaxDynamicSharedMemorySize, 163840);

    // ---- prep
    conv_pad<<<dim3(1, 4096), 256, 0, stream>>>(Wih1, W0, 4096, IN_, 160);
    conv_pad<<<dim3(4, 4096), 256, 0, stream>>>(Whh1, Wb + 0 * WSZ, 4096, H_, H_);
    conv_pad<<<dim3(4, 4096), 256, 0, stream>>>(Wih2, Wb + 1 * WSZ, 4096, H_, H_);
    conv_pad<<<dim3(4, 4096), 256, 0, stream>>>(Whh2, Wb + 2 * WSZ, 4096, H_, H_);
    conv_pad<<<dim3(4, 4096), 256, 0, stream>>>(Wih3, Wb + 3 * WSZ, 4096, H_, H_);
    conv_pad<<<dim3(4, 4096), 256, 0, stream>>>(Whh3, Wb + 4 * WSZ, 4096, H_, H_);
    conv_pad<<<dim3(4, 160), 256, 0, stream>>>(Wd, Wd16, OUT_, H_, H_);
    convT_kernel<<<dim3(1, 1024), 256, 0, stream>>>(Wd, WdT);
    seq_pad<<<dim3(1, B_ * T_), 256, 0, stream>>>(seq, seq16);
    bias_add_kernel<<<16, 256, 0, stream>>>(bih1, bhh1, bias_comb + 0 * 4096, 4096);
    bias_add_kernel<<<16, 256, 0, stream>>>(bih2, bhh2, bias_comb + 1 * 4096, 4096);
    bias_add_kernel<<<16, 256, 0, stream>>>(bih3, bhh3, bias_comb + 2 * 4096, 4096);
    bfb_kernel<<<16, 256, 0, stream>>>(Wih1, bd, bfb);
    wfb_mfma<<<dim3(32, 8), 256, 0, stream>>>(W0, WdT, Wfb);
    zero_kernel<<<512, 256, 0, stream>>>((float*)h01a, zero_floats);

    f16 *hc = h01a, *hn = h01b;
    for (int t = 0; t < T_; ++t) {
        const f16* hfb   = (t > 0) ? (hist + (size_t)(t - 1) * BH) : hc;  // unused at t=0
        const f16* h2old = (t > 0) ? (hist + (size_t)(t - 1) * BH) : hc;  // zeros at t=0
        step_mfma<<<dim3(64, 3), 512, 163840, stream>>>(
            seq16, hfb, h2old, hc, hn, hist + (size_t)t * BH, c_st,
            W0, Wb, Wfb, bias_comb, bfb, cnum, gnum, t);
        f16* tmp = hc; hc = hn; hn = tmp;
    }

    decode_mfma<<<dim3(200, 5), 256, 0, stream>>>(hist, Wd16, bd, (float*)d_out);
}

// Round 3
// 3019.657 us; speedup vs baseline: 1.2333x; 1.2333x over previous
//
#include <hip/hip_runtime.h>
#include <math.h>

// Problem constants
#define B_   256
#define T_   100
#define IN_  132
#define OUT_ 132
#define H_   1024
#define BH   ((size_t)B_ * H_)

typedef _Float16 f16;
typedef _Float16 f16x8 __attribute__((ext_vector_type(8)));
typedef float    f32x4 __attribute__((ext_vector_type(4)));

#define MFMA16(a, b, c) __builtin_amdgcn_mfma_f32_16x16x32_f16((a), (b), (c), 0, 0, 0)

#define AS1 __attribute__((address_space(1)))
#define AS3 __attribute__((address_space(3)))

__device__ __forceinline__ void gl_lds16(const void* g, void* l) {
    __builtin_amdgcn_global_load_lds((AS1 void*)g, (AS3 void*)l, 16, 0, 0);
}

__device__ __forceinline__ float sigmoidf_(float x) {
    return 1.0f / (1.0f + __expf(-x));
}
__device__ __forceinline__ float tanhf_(float x) {
    float e = __expf(2.0f * x);
    return 1.0f - 2.0f / (e + 1.0f);
}

// ---------------- prep kernels ----------------

__global__ void conv_pad(const float* __restrict__ src, f16* __restrict__ dst,
                         int src_rows, int src_k, int dst_k) {
    int k = blockIdx.x * 256 + threadIdx.x;
    int r = blockIdx.y;
    if (k >= dst_k) return;
    float v = (r < src_rows && k < src_k) ? src[(size_t)r * src_k + k] : 0.0f;
    dst[(size_t)r * dst_k + k] = (f16)v;
}

// WdT[m][k] = Wd[k][m], padded to k<160. grid (1, 1024), block 256
__global__ void convT_kernel(const float* __restrict__ Wd, f16* __restrict__ WdT) {
    int k = blockIdx.x * 256 + threadIdx.x;
    int m = blockIdx.y;
    if (k >= 160) return;
    float v = (k < IN_) ? Wd[(size_t)k * H_ + m] : 0.0f;
    WdT[(size_t)m * 160 + k] = (f16)v;
}

__global__ void bias_add_kernel(const float* __restrict__ a, const float* __restrict__ b,
                                float* __restrict__ dst, int n) {
    int i = blockIdx.x * 256 + threadIdx.x;
    if (i < n) dst[i] = a[i] + b[i];
}

// bfb[j] = sum_k Wih1[j][k] * bd[k]
__global__ void bfb_kernel(const float* __restrict__ Wih1, const float* __restrict__ bd,
                           float* __restrict__ bfb) {
    int j = blockIdx.x * 256 + threadIdx.x;
    if (j >= 4096) return;
    float s = 0.0f;
    for (int k = 0; k < IN_; ++k) s += Wih1[(size_t)j * IN_ + k] * bd[k];
    bfb[j] = s;
}

__global__ void zero_kernel(float* __restrict__ p, int n) {
    int i = blockIdx.x * blockDim.x + threadIdx.x;
    int st = gridDim.x * blockDim.x;
    for (; i < n; i += st) p[i] = 0.0f;
}

// Pack a fp32 [4096][1024] weight into staged layout:
// Wpk[wsel][jt][kt][c(128 rows)][64B], col c -> gate=(c>>4)&3, jj=(c&15)+(c>>6)*16,
// source row = gate*1024 + jt*32 + jj, k = kt*32 + ch*8 + e  (plain chunk order;
// XOR swizzle is applied on the per-lane source address at stage time).
// grid (32 jt, 32 kt), block 256.
__global__ __launch_bounds__(256) void pack_w(const float* __restrict__ W,
                                              f16* __restrict__ Wpk, int wsel) {
    int jt = blockIdx.x, kt = blockIdx.y;
    f16* dst = Wpk + (((size_t)wsel * 32 + jt) * 32 + kt) * 4096;
    for (int u = threadIdx.x; u < 512; u += 256) {
        int c = u >> 2, ch = u & 3;
        int gate = (c >> 4) & 3, jj = (c & 15) + (c >> 6) * 16;
        const float* s = W + ((size_t)gate * 1024 + jt * 32 + jj) * 1024 + kt * 32 + ch * 8;
        f16x8 v;
#pragma unroll
        for (int e = 0; e < 8; ++e) v[e] = (f16)s[e];
        *(f16x8*)(dst + (size_t)u * 8) = v;
    }
}

// Same but f16 source (for Wfb).
__global__ __launch_bounds__(256) void pack_wf16(const f16* __restrict__ W,
                                                 f16* __restrict__ Wpk, int wsel) {
    int jt = blockIdx.x, kt = blockIdx.y;
    f16* dst = Wpk + (((size_t)wsel * 32 + jt) * 32 + kt) * 4096;
    for (int u = threadIdx.x; u < 512; u += 256) {
        int c = u >> 2, ch = u & 3;
        int gate = (c >> 4) & 3, jj = (c & 15) + (c >> 6) * 16;
        const f16* s = W + ((size_t)gate * 1024 + jt * 32 + jj) * 1024 + kt * 32 + ch * 8;
        f16x8 v = *(const f16x8*)s;
        *(f16x8*)(dst + (size_t)u * 8) = v;
    }
}

// Pack Wih1 fp32 [4096][132] -> W0pk[jt][kt(5)][4096], k padded to 160.
// grid (32 jt, 5 kt), block 256.
__global__ __launch_bounds__(256) void pack_w0(const float* __restrict__ W,
                                               f16* __restrict__ W0pk) {
    int jt = blockIdx.x, kt = blockIdx.y;
    f16* dst = W0pk + ((size_t)jt * 5 + kt) * 4096;
    for (int u = threadIdx.x; u < 512; u += 256) {
        int c = u >> 2, ch = u & 3;
        int gate = (c >> 4) & 3, jj = (c & 15) + (c >> 6) * 16;
        int row = gate * 1024 + jt * 32 + jj;
        f16x8 v;
#pragma unroll
        for (int e = 0; e < 8; ++e) {
            int k = kt * 32 + ch * 8 + e;
            v[e] = (f16)((k < IN_) ? W[(size_t)row * IN_ + k] : 0.0f);
        }
        *(f16x8*)(dst + (size_t)u * 8) = v;
    }
}

// Pack seq fp32 [B][T][IN] -> seqpk[t][kt(5)][256 b][32] f16. grid (5, 100), block 256.
__global__ __launch_bounds__(256) void pack_seq(const float* __restrict__ seq,
                                                f16* __restrict__ seqpk) {
    int kt = blockIdx.x, t = blockIdx.y;
    int b = threadIdx.x;
    f16* d = seqpk + (((size_t)t * 5 + kt) * 256 + b) * 32;
#pragma unroll
    for (int ch = 0; ch < 4; ++ch) {
        f16x8 v;
#pragma unroll
        for (int e = 0; e < 8; ++e) {
            int k = kt * 32 + ch * 8 + e;
            v[e] = (f16)((k < IN_) ? seq[((size_t)b * T_ + t) * IN_ + k] : 0.0f);
        }
        *(f16x8*)(d + ch * 8) = v;
    }
}

// Wfb = W0(fp16,[4096][160]) @ WdT(fp16,[1024][160])^T -> [4096][1024] fp16
// grid (32 m-tiles, 8 n-tiles), block 256 (4 waves 2x2 of 64x64). One-time prep.
__global__ __launch_bounds__(256) void wfb_mfma(
    const f16* __restrict__ W0, const f16* __restrict__ WdT, f16* __restrict__ Wfb)
{
    const int m0 = blockIdx.x * 128;
    const int n0 = blockIdx.y * 128;
    const int tid  = threadIdx.x;
    const int lane = tid & 63;
    const int w    = tid >> 6;
    const int lx   = lane & 15;
    const int quad = lane >> 4;
    const int wrow = w >> 1, wcol = w & 1;

    __shared__ __align__(16) char lds[32768];   // 2 x (A 8KB + B 8KB)

    auto stA = [&](int kt, int buf) {
        char* base = lds + buf * 16384;
#pragma unroll
        for (int i = 0; i < 2; ++i) {
            int r  = w * 32 + i * 16 + (lane >> 2);
            int sg = (lane & 3) ^ (r & 3);
            const f16* g = W0 + (size_t)(m0 + r) * 160 + kt * 32 + sg * 8;
            gl_lds16(g, base + (size_t)(w * 32 + i * 16) * 64);
        }
    };
    auto stB = [&](int kt, int buf) {
        char* base = lds + 8192 + buf * 16384;
#pragma unroll
        for (int i = 0; i < 2; ++i) {
            int r  = w * 32 + i * 16 + (lane >> 2);
            int sg = (lane & 3) ^ (r & 3);
            const f16* g = WdT + (size_t)(n0 + r) * 160 + kt * 32 + sg * 8;
            gl_lds16(g, base + (size_t)(w * 32 + i * 16) * 64);
        }
    };

    f32x4 acc[4][4];
#pragma unroll
    for (int m = 0; m < 4; ++m)
#pragma unroll
        for (int n = 0; n < 4; ++n) acc[m][n] = (f32x4){0.f, 0.f, 0.f, 0.f};

    stA(0, 0); stB(0, 0);
    for (int kt = 0; kt < 5; ++kt) {
        __syncthreads();
        if (kt + 1 < 5) { stA(kt + 1, (kt + 1) & 1); stB(kt + 1, (kt + 1) & 1); }
        const char* bA = lds + (kt & 1) * 16384;
        const char* bB = lds + 8192 + (kt & 1) * 16384;
        f16x8 af[4], bf[4];
#pragma unroll
        for (int m = 0; m < 4; ++m) {
            int R = wrow * 64 + m * 16 + lx;
            af[m] = *(const f16x8*)(bA + R * 64 + ((quad ^ (R & 3)) * 16));
        }
#pragma unroll
        for (int n = 0; n < 4; ++n) {
            int R = wcol * 64 + n * 16 + lx;
            bf[n] = *(const f16x8*)(bB + R * 64 + ((quad ^ (R & 3)) * 16));
        }
#pragma unroll
        for (int m = 0; m < 4; ++m)
#pragma unroll
            for (int n = 0; n < 4; ++n)
                acc[m][n] = MFMA16(af[m], bf[n], acc[m][n]);
    }

#pragma unroll
    for (int m = 0; m < 4; ++m)
#pragma unroll
        for (int n = 0; n < 4; ++n)
#pragma unroll
            for (int r = 0; r < 4; ++r) {
                int row = m0 + wrow * 64 + m * 16 + quad * 4 + r;
                int col = n0 + wcol * 64 + n * 16 + lx;
                Wfb[(size_t)row * H_ + col] = (f16)acc[m][n][r];
            }
}

// ---------------- fused per-step kernel ----------------
// grid (32 j-tiles, 4 m-tiles(64 rows), 3 cells), block 256 (4 waves 2x2).
// Tile: 64 batch x 128 cols; col c -> gate=(c>>4)&3, jj=(c&15)+(c>>6)*16.
// ALL staging loads are contiguous 1KB (pre-packed weights + k-chunk-packed h),
// XOR-swizzle applied on per-lane source address; LDS dest linear.
// K-loop: phase0 (x/h_{l-1}/h2fb) then phase1 (h_l @ Whh), flat; 3-deep
// counted-vmcnt pipeline, 4 LDS buffers, 3 loads/wave/stage -> steady vmcnt(6).
__global__ __launch_bounds__(256) void step_mfma(
    const f16* __restrict__ seqpk,    // [T][5][256][32]
    const f16* __restrict__ h2pkP,    // [32][256][32] prev h2 packed (zeros at t=0)
    const f16* __restrict__ h01pkC,   // [2][32][256][32] old h0,h1 packed
    f16* __restrict__ h01pkN,         // [2][32][256][32] new h0,h1 packed
    f16* __restrict__ h2pkN,          // [32][256][32] new h2 packed
    f16* __restrict__ histN,          // [256][1024] linear h2 for decode (hist + t*BH)
    float* __restrict__ c_st,         // [3][B][H]
    const f16* __restrict__ W0pk,     // [32 jt][5 kt][4096]
    const f16* __restrict__ Wpk,      // [6 wsel][32 jt][32 kt][4096]
    const float* __restrict__ bias_comb,  // [3][4096]
    const float* __restrict__ bfb,        // [4096]
    const int* __restrict__ cnum, const int* __restrict__ gnum,
    int t)
{
    const int jt   = blockIdx.x;
    const int mb   = blockIdx.y;
    const int l    = blockIdx.z;
    const int tid  = threadIdx.x;
    const int lane = tid & 63;
    const int w    = tid >> 6;
    const int lx   = lane & 15;
    const int quad = lane >> 4;
    const int wrow = w >> 1, wcol = w & 1;

    __shared__ __align__(16) char lds[49152];   // 4 x (A 4KB + B 8KB)

    // ---- operand decode (byte pointers; per-kt strides: A 16KB, B 8KB)
    bool use_gt = false;
    int n0 = 32;
    const char *A0 = nullptr, *B0 = nullptr;
    const char* wb = (const char*)Wpk + (size_t)jt * 262144;   // + wsel*8MB
    if (l == 0) {
        int cn = cnum[0], gn = gnum[0];
        use_gt = (t % (cn + gn)) < gn;
        if (use_gt)      { A0 = (const char*)(seqpk + (size_t)t * 5 * 8192);
                           B0 = (const char*)(W0pk + (size_t)jt * 5 * 4096); n0 = 5; }
        else if (t == 0) { n0 = 0; }
        else             { A0 = (const char*)h2pkP; B0 = wb + (size_t)5 * 8388608; }
    } else if (l == 1) { A0 = (const char*)h01pkC;        B0 = wb + (size_t)1 * 8388608; }
    else               { A0 = (const char*)(h01pkC + BH); B0 = wb + (size_t)3 * 8388608; }
    const char* A1 = (l == 0) ? (const char*)h01pkC
                   : (l == 1) ? (const char*)(h01pkC + BH) : (const char*)h2pkP;
    const char* B1 = wb + (size_t)((l == 0) ? 0 : (l == 1) ? 2 : 4) * 8388608;
    const int ntot = n0 + 32;

    // ---- per-lane source offset within a contiguous 1KB chunk (XOR swizzle on source)
    const int lr = lane >> 2, lc = lane & 3;
    const int perl = lr * 64 + ((lc ^ (lr & 3)) * 16);

    auto stage = [&](int kt, int buf) {
        const char *pA, *pB; int kk;
        if (kt < n0) { kk = kt;      pA = A0; pB = B0; }
        else         { kk = kt - n0; pA = A1; pB = B1; }
        char* base = lds + buf * 12288;
        gl_lds16(pA + (size_t)kk * 16384 + (size_t)(mb * 64 + w * 16) * 64 + perl,
                 base + w * 1024);
#pragma unroll
        for (int i = 0; i < 2; ++i)
            gl_lds16(pB + (size_t)kk * 8192 + (size_t)(w * 2 + i) * 1024 + perl,
                     base + 4096 + (size_t)(w * 2 + i) * 1024);
    };

    f32x4 acc[2][4];
#pragma unroll
    for (int m = 0; m < 2; ++m)
#pragma unroll
        for (int n = 0; n < 4; ++n) acc[m][n] = (f32x4){0.f, 0.f, 0.f, 0.f};

    // ---- 3-deep prologue (ntot >= 32 always)
    stage(0, 0);
    stage(1, 1);
    stage(2, 2);

    for (int kt = 0; kt < ntot; ++kt) {
        if (kt < ntot - 2)       asm volatile("s_waitcnt vmcnt(6)" ::: "memory");
        else if (kt == ntot - 2) asm volatile("s_waitcnt vmcnt(3)" ::: "memory");
        else                     asm volatile("s_waitcnt vmcnt(0)" ::: "memory");
        __builtin_amdgcn_s_barrier();              // stage kt visible to all waves

        const char* bA = lds + (kt & 3) * 12288;
        const char* bB = bA + 4096;
        f16x8 af[2], bf[4];
#pragma unroll
        for (int m = 0; m < 2; ++m) {
            int R = wrow * 32 + m * 16 + lx;
            af[m] = *(const f16x8*)(bA + R * 64 + ((quad ^ (R & 3)) * 16));
        }
#pragma unroll
        for (int n = 0; n < 4; ++n) {
            int R = wcol * 64 + n * 16 + lx;
            bf[n] = *(const f16x8*)(bB + R * 64 + ((quad ^ (R & 3)) * 16));
        }
        asm volatile("s_waitcnt lgkmcnt(0)" ::: "memory");
        __builtin_amdgcn_sched_barrier(0);
        __builtin_amdgcn_s_barrier();              // reads done -> safe to overwrite

        if (kt + 3 < ntot) stage(kt + 3, (kt + 3) & 3);

        __builtin_amdgcn_s_setprio(1);
#pragma unroll
        for (int m = 0; m < 2; ++m)
#pragma unroll
            for (int n = 0; n < 4; ++n)
                acc[m][n] = MFMA16(af[m], bf[n], acc[m][n]);
        __builtin_amdgcn_s_setprio(0);
    }

    // ---- lane-local LSTM epilogue (C layout: col=lane&15, row=quad*4+r; gate=n)
    const int j = jt * 32 + wcol * 16 + lx;
    const float* bc = bias_comb + l * 4096;
    const bool addfb = (l == 0 && !use_gt && t > 0);
    float bi  = bc[j]        + (addfb ? bfb[j]        : 0.f);
    float bff = bc[1024 + j] + (addfb ? bfb[1024 + j] : 0.f);
    float bg  = bc[2048 + j] + (addfb ? bfb[2048 + j] : 0.f);
    float bo  = bc[3072 + j] + (addfb ? bfb[3072 + j] : 0.f);
#pragma unroll
    for (int m = 0; m < 2; ++m) {
#pragma unroll
        for (int r = 0; r < 4; ++r) {
            int b = mb * 64 + wrow * 32 + m * 16 + quad * 4 + r;
            float gi = acc[m][0][r] + bi;
            float gf = acc[m][1][r] + bff;
            float gg = acc[m][2][r] + bg;
            float go = acc[m][3][r] + bo;
            size_t ix = ((size_t)l * B_ + b) * H_ + j;
            float cn = sigmoidf_(gf) * c_st[ix] + sigmoidf_(gi) * tanhf_(gg);
            c_st[ix] = cn;
            float hv = sigmoidf_(go) * tanhf_(cn);
            f16 hv16 = (f16)hv;
            size_t pix = ((size_t)(j >> 5) * 256 + b) * 32 + (j & 31);   // packed
            if (l == 2) { h2pkN[pix] = hv16; histN[(size_t)b * H_ + j] = hv16; }
            else        h01pkN[(size_t)l * BH + pix] = hv16;
        }
    }
}

// ---------------- final batched decoder ----------------
// out[b][t][n] = hist[t][b][:] @ Wd^T + bd. M=25600 rows (t*256+b), N=160(132), K=1024.
// grid (200, 5), block 256 (4 waves stacked on M; tile 128x32).
__global__ __launch_bounds__(256) void decode_mfma(
    const f16* __restrict__ hist,   // [100][256][1024]
    const f16* __restrict__ Wd16,   // [160][1024]
    const float* __restrict__ bd,   // [132]
    float* __restrict__ dout)       // [256][T*132]
{
    const int r0  = blockIdx.x * 128;
    const int nb0 = blockIdx.y * 32;
    const int tid  = threadIdx.x;
    const int lane = tid & 63;
    const int w    = tid >> 6;
    const int lx   = lane & 15;
    const int quad = lane >> 4;

    __shared__ __align__(16) char lds[20480];   // 2 x (A 8KB + B 2KB)

    auto stA = [&](int kt, int buf) {
        char* base = lds + buf * 10240;
#pragma unroll
        for (int i = 0; i < 2; ++i) {
            int r  = w * 32 + i * 16 + (lane >> 2);
            int sg = (lane & 3) ^ (r & 3);
            const f16* g = hist + (size_t)(r0 + r) * H_ + kt * 32 + sg * 8;
            gl_lds16(g, base + (size_t)(w * 32 + i * 16) * 64);
        }
    };
    auto stB = [&](int kt, int buf) {
        char* base = lds + 8192 + buf * 10240;
        if (w < 2) {
            int r  = w * 16 + (lane >> 2);
            int sg = (lane & 3) ^ (r & 3);
            const f16* g = Wd16 + (size_t)(nb0 + r) * H_ + kt * 32 + sg * 8;
            gl_lds16(g, base + (size_t)(w * 16) * 64);
        }
    };

    f32x4 acc[2][2];
#pragma unroll
    for (int m = 0; m < 2; ++m)
#pragma unroll
        for (int n = 0; n < 2; ++n) acc[m][n] = (f32x4){0.f, 0.f, 0.f, 0.f};

    stA(0, 0); stB(0, 0);
    for (int kt = 0; kt < 32; ++kt) {
        __syncthreads();
        if (kt + 1 < 32) { stA(kt + 1, (kt + 1) & 1); stB(kt + 1, (kt + 1) & 1); }
        const char* bA = lds + (kt & 1) * 10240;
        const char* bB = lds + 8192 + (kt & 1) * 10240;
        f16x8 af[2], bf[2];
#pragma unroll
        for (int m = 0; m < 2; ++m) {
            int R = w * 32 + m * 16 + lx;
            af[m] = *(const f16x8*)(bA + R * 64 + ((quad ^ (R & 3)) * 16));
        }
#pragma unroll
        for (int n = 0; n < 2; ++n) {
            int R = n * 16 + lx;
            bf[n] = *(const f16x8*)(bB + R * 64 + ((quad ^ (R & 3)) * 16));
        }
#pragma unroll
        for (int m = 0; m < 2; ++m)
#pragma unroll
            for (int n = 0; n < 2; ++n)
                acc[m][n] = MFMA16(af[m], bf[n], acc[m][n]);
    }

#pragma unroll
    for (int n = 0; n < 2; ++n) {
        int nn = nb0 + n * 16 + lx;
        if (nn < OUT_) {
            float bv = bd[nn];
#pragma unroll
            for (int m = 0; m < 2; ++m)
#pragma unroll
                for (int r = 0; r < 4; ++r) {
                    int row = r0 + w * 32 + m * 16 + quad * 4 + r;
                    int tt = row >> 8, b = row & 255;
                    dout[(size_t)b * (T_ * OUT_) + (size_t)tt * OUT_ + nn] = acc[m][n][r] + bv;
                }
        }
    }
}

// ---------------- host launch ----------------

extern "C" void kernel_launch(void* const* d_in, const int* in_sizes, int n_in,
                              void* d_out, int out_size, void* d_ws, size_t ws_size,
                              hipStream_t stream) {
    const float* seq  = (const float*)d_in[0];
    const float* Wih1 = (const float*)d_in[1];
    const float* Whh1 = (const float*)d_in[2];
    const float* bih1 = (const float*)d_in[3];
    const float* bhh1 = (const float*)d_in[4];
    const float* Wih2 = (const float*)d_in[5];
    const float* Whh2 = (const float*)d_in[6];
    const float* bih2 = (const float*)d_in[7];
    const float* bhh2 = (const float*)d_in[8];
    const float* Wih3 = (const float*)d_in[9];
    const float* Whh3 = (const float*)d_in[10];
    const float* bih3 = (const float*)d_in[11];
    const float* bhh3 = (const float*)d_in[12];
    const float* Wd   = (const float*)d_in[13];
    const float* bd   = (const float*)d_in[14];
    const int*   cnum = (const int*)d_in[15];
    const int*   gnum = (const int*)d_in[16];

    // ---- workspace layout
    char* p = (char*)d_ws;
    f16*  W0   = (f16*)p;  p += (size_t)4096 * 160 * 2;          // 1.31 MB
    f16*  Wd16 = (f16*)p;  p += (size_t)160 * 1024 * 2;          // 0.33 MB
    f16*  WdT  = (f16*)p;  p += (size_t)1024 * 160 * 2;          // 0.33 MB
    f16*  Wfb  = (f16*)p;  p += (size_t)4096 * 1024 * 2;         // 8.39 MB
    float* bias_comb = (float*)p; p += (size_t)3 * 4096 * 4;     // 48 KB
    float* bfb = (float*)p; p += (size_t)4096 * 4;               // 16 KB
    f16*  hist = (f16*)p;  p += (size_t)100 * BH * 2;            // 52.4 MB
    // zero region start: h01pkA + h2pkA + c_st (contiguous)
    f16*  h01pkA = (f16*)p; p += (size_t)2 * BH * 2;             // 1.05 MB
    f16*  h2pkA  = (f16*)p; p += (size_t)BH * 2;                 // 0.52 MB
    float* c_st  = (float*)p; p += (size_t)3 * BH * 4;           // 3.15 MB
    f16*  h01pkB = (f16*)p; p += (size_t)2 * BH * 2;             // 1.05 MB
    f16*  h2pkB  = (f16*)p; p += (size_t)BH * 2;                 // 0.52 MB
    f16*  Wpk   = (f16*)p; p += (size_t)6 * 32 * 32 * 4096 * 2;  // 50.3 MB
    f16*  W0pk  = (f16*)p; p += (size_t)32 * 5 * 4096 * 2;       // 1.31 MB
    f16*  seqpk = (f16*)p; p += (size_t)T_ * 5 * 256 * 32 * 2;   // 8.19 MB

    const int zero_floats = (int)(((size_t)3 * BH * 2 + (size_t)3 * BH * 4) / 4);

    // ---- prep
    conv_pad<<<dim3(1, 4096), 256, 0, stream>>>(Wih1, W0, 4096, IN_, 160);
    conv_pad<<<dim3(4, 160), 256, 0, stream>>>(Wd, Wd16, OUT_, H_, H_);
    convT_kernel<<<dim3(1, 1024), 256, 0, stream>>>(Wd, WdT);
    bias_add_kernel<<<16, 256, 0, stream>>>(bih1, bhh1, bias_comb + 0 * 4096, 4096);
    bias_add_kernel<<<16, 256, 0, stream>>>(bih2, bhh2, bias_comb + 1 * 4096, 4096);
    bias_add_kernel<<<16, 256, 0, stream>>>(bih3, bhh3, bias_comb + 2 * 4096, 4096);
    bfb_kernel<<<16, 256, 0, stream>>>(Wih1, bd, bfb);
    wfb_mfma<<<dim3(32, 8), 256, 0, stream>>>(W0, WdT, Wfb);
    // packed weights: wsel {0:Whh1, 1:Wih2, 2:Whh2, 3:Wih3, 4:Whh3, 5:Wfb}
    pack_w<<<dim3(32, 32), 256, 0, stream>>>(Whh1, Wpk, 0);
    pack_w<<<dim3(32, 32), 256, 0, stream>>>(Wih2, Wpk, 1);
    pack_w<<<dim3(32, 32), 256, 0, stream>>>(Whh2, Wpk, 2);
    pack_w<<<dim3(32, 32), 256, 0, stream>>>(Wih3, Wpk, 3);
    pack_w<<<dim3(32, 32), 256, 0, stream>>>(Whh3, Wpk, 4);
    pack_wf16<<<dim3(32, 32), 256, 0, stream>>>(Wfb, Wpk, 5);
    pack_w0<<<dim3(32, 5), 256, 0, stream>>>(Wih1, W0pk);
    pack_seq<<<dim3(5, T_), 256, 0, stream>>>(seq, seqpk);
    zero_kernel<<<512, 256, 0, stream>>>((float*)h01pkA, zero_floats);

    f16 *h01C = h01pkA, *h01N = h01pkB, *h2P = h2pkA, *h2N = h2pkB;
    for (int t = 0; t < T_; ++t) {
        step_mfma<<<dim3(32, 4, 3), 256, 0, stream>>>(
            seqpk, h2P, h01C, h01N, h2N, hist + (size_t)t * BH, c_st,
            W0pk, Wpk, bias_comb, bfb, cnum, gnum, t);
        f16* tmp;
        tmp = h01C; h01C = h01N; h01N = tmp;
        tmp = h2P;  h2P  = h2N;  h2N  = tmp;
    }

    decode_mfma<<<dim3(200, 5), 256, 0, stream>>>(hist, Wd16, bd, (float*)d_out);
}